// Round 12
// baseline (153.484 us; speedup 1.0000x reference)
//
#include <hip/hip_runtime.h>
#include <cstdint>

typedef unsigned short u16;
typedef unsigned int u32;
typedef __attribute__((ext_vector_type(8))) short short8;
typedef __attribute__((ext_vector_type(4))) float f32x4;

static constexpr int Bc = 2, Sc = 2048, DMc = 1024, Hc = 16, DKc = 64;
static constexpr int Mc = Bc * Sc; // 4096
static constexpr int BHSc = Bc * Hc * Sc; // 65536 q-rows

#if __has_builtin(__builtin_amdgcn_exp2f)
#define EXP2F(x) __builtin_amdgcn_exp2f(x)
#else
#define EXP2F(x) exp2f(x)
#endif

__device__ __forceinline__ float b2f(u16 u) { return __uint_as_float((u32)u << 16); }
__device__ __forceinline__ u16 f2b(float f) {
  u32 x = __float_as_uint(f);
  return (u16)((x + 0x7fffu + ((x >> 16) & 1u)) >> 16);
}
// single-instruction packed f32x2 -> bf16x2 (RTNE)
__device__ __forceinline__ u32 cvtpk(float lo, float hi) {
  u32 r;
  asm("v_cvt_pk_bf16_f32 %0, %1, %2" : "=v"(r) : "v"(lo), "v"(hi));
  return r;
}

// ---------------- f32 -> bf16 conversion (RTNE), all 3 inputs in one launch ---
__global__ __launch_bounds__(256)
void cvt3_k(const float* __restrict__ x, const float* __restrict__ qw,
            const float* __restrict__ ow,
            u16* __restrict__ xb, u16* __restrict__ qwb, u16* __restrict__ owb)
{
  const int i = blockIdx.x * 256 + threadIdx.x; // 1048576 total, 8 elems each
  const float* src; u16* dst; int j;
  if (i < 524288)      { src = x;  dst = xb;  j = i; }
  else if (i < 917504) { src = qw; dst = qwb; j = i - 524288; }
  else                 { src = ow; dst = owb; j = i - 917504; }
  const float4 a = *(const float4*)(src + (size_t)j * 8);
  const float4 b = *(const float4*)(src + (size_t)j * 8 + 4);
  uint4 o;
  o.x = cvtpk(a.x, a.y);
  o.y = cvtpk(a.z, a.w);
  o.z = cvtpk(b.x, b.y);
  o.w = cvtpk(b.z, b.w);
  *(uint4*)(dst + (size_t)j * 8) = o;
}

// ---------------- GEMM: C[M][N] = A[M][K] * W[N][K]^T, bf16 in, f32 acc -------
template <typename OutT>
__global__ __launch_bounds__(256, 2)
void gemm_bt128(const u16* __restrict__ A, const u16* __restrict__ W,
                OutT* __restrict__ C, int M, int N, int K)
{
  __shared__ u16 As[128 * 32];
  __shared__ u16 Bs[128 * 32];
  const int t = threadIdx.x;
  const int w = t >> 6, l = t & 63;
  const int wr = w >> 1, wc = w & 1;
  const int l4 = l >> 4, l15 = l & 15;
  const int bm = blockIdx.x, bn = blockIdx.y;

  f32x4 acc[4][4] = {};

  const int rowA = bm * 128, rowB = bn * 128;
  const int sr = l >> 2, sk = (l & 3) * 8;

  for (int k0 = 0; k0 < K; k0 += 32) {
    __syncthreads();
#pragma unroll
    for (int i = 0; i < 2; ++i) {
      const int chunk = i * 4 + w;
      const u16* ga = A + (size_t)(rowA + chunk * 16 + sr) * K + k0 + sk;
      const u16* gb = W + (size_t)(rowB + chunk * 16 + sr) * K + k0 + sk;
      __builtin_amdgcn_global_load_lds((const __attribute__((address_space(1))) void*)ga,
                                       (__attribute__((address_space(3))) void*)(As + chunk * 512), 16, 0, 0);
      __builtin_amdgcn_global_load_lds((const __attribute__((address_space(1))) void*)gb,
                                       (__attribute__((address_space(3))) void*)(Bs + chunk * 512), 16, 0, 0);
    }
    __syncthreads();
    short8 af[4], bf[4];
#pragma unroll
    for (int m = 0; m < 4; ++m)
      af[m] = *(const short8*)(As + (wr * 64 + m * 16 + l15) * 32 + l4 * 8);
#pragma unroll
    for (int n = 0; n < 4; ++n)
      bf[n] = *(const short8*)(Bs + (wc * 64 + n * 16 + l15) * 32 + l4 * 8);
#pragma unroll
    for (int m = 0; m < 4; ++m)
#pragma unroll
      for (int n = 0; n < 4; ++n)
        acc[m][n] = __builtin_amdgcn_mfma_f32_16x16x32_bf16(af[m], bf[n], acc[m][n], 0, 0, 0);
  }

#pragma unroll
  for (int m = 0; m < 4; ++m) {
    const int r0 = rowA + wr * 64 + m * 16 + l4 * 4;
#pragma unroll
    for (int n = 0; n < 4; ++n) {
      const int c0 = rowB + wc * 64 + n * 16 + l15;
#pragma unroll
      for (int r = 0; r < 4; ++r) {
        const float v = acc[m][n][r];
        if constexpr (sizeof(OutT) == 2)
          C[(size_t)(r0 + r) * N + c0] = (OutT)f2b(v);
        else
          C[(size_t)(r0 + r) * N + c0] = (OutT)v;
      }
    }
  }
}

// ---------------- RoPE cos/sin table: [S][32] float2 --------------------------
__global__ void rope_table_k(float2* __restrict__ tab)
{
  const int idx = blockIdx.x * 256 + threadIdx.x;
  const int p = idx >> 5, i = idx & 31;
  const float invf = powf(10000.0f, -(float)(2 * i) / 64.0f);
  const float ang = (float)p * invf;
  tab[idx] = make_float2(cosf(ang), sinf(ang));
}

// ---------------- RoPE apply + relayout ---------------------------------------
// Q is scaled by 0.125*log2(e) so attention scores are in the exp2 domain.
__global__ __launch_bounds__(256)
void rope_reshape_k(const u16* __restrict__ qkv, const int* __restrict__ tokpos,
                    const float2* __restrict__ tab,
                    u16* __restrict__ Q, u16* __restrict__ K, u16* __restrict__ Vt)
{
  __shared__ u16 Vs[64][72];
  const int t = threadIdx.x;
  const int st = blockIdx.x, h = blockIdx.y, b = blockIdx.z;

  {
    const int sl = t >> 2, iq = t & 3;
    const int s = st * 64 + sl;
    const int p = tokpos[b * Sc + s];
    const size_t row = (size_t)(b * Sc + s) * 3 * DMc + h * DKc + iq * 16;
    const size_t orow = ((size_t)(b * Hc + h) * Sc + s) * DKc + iq * 16;
#pragma unroll
    for (int which = 0; which < 2; ++which) {
      const u16* g = qkv + row + which * DMc;
      uint4 va = *(const uint4*)g;
      uint4 vb = *(const uint4*)(g + 8);
      u32 in[8] = {va.x, va.y, va.z, va.w, vb.x, vb.y, vb.z, vb.w};
      const float scale = (which == 0) ? 0.18033688011112f : 1.0f; // 0.125*log2e
      u32 ow[8];
#pragma unroll
      for (int j = 0; j < 8; ++j) {
        const float2 cs = tab[p * 32 + iq * 8 + j];
        const float t1 = b2f((u16)(in[j] & 0xffffu));
        const float t2 = b2f((u16)(in[j] >> 16));
        ow[j] = cvtpk((t1 * cs.x - t2 * cs.y) * scale, (t1 * cs.y + t2 * cs.x) * scale);
      }
      u16* dst = (which == 0 ? Q : K) + orow;
      *(uint4*)dst = make_uint4(ow[0], ow[1], ow[2], ow[3]);
      *(uint4*)(dst + 8) = make_uint4(ow[4], ow[5], ow[6], ow[7]);
    }
  }
#pragma unroll
  for (int it = 0; it < 2; ++it) {
    const int sv = it * 32 + (t >> 3);
    const int d0 = (t & 7) * 8;
    const u16* g = qkv + (size_t)(b * Sc + st * 64 + sv) * 3 * DMc + 2 * DMc + h * DKc + d0;
    *(uint4*)&Vs[sv][d0] = *(const uint4*)g;
  }
  __syncthreads();
  {
    const int d = t >> 2, s0 = (t & 3) * 16;
    u16 tmp[16];
#pragma unroll
    for (int j = 0; j < 16; ++j) tmp[j] = Vs[s0 + j][d];
    u16* dst = Vt + ((size_t)(b * Hc + h) * DKc + d) * Sc + st * 64 + s0;
    *(uint4*)dst = *(const uint4*)tmp;
    *(uint4*)(dst + 8) = *(const uint4*)(tmp + 8);
  }
}

// ---------------- causal flash attention, 128-row tiles, 4-way kv split -------
// 1024 blocks = (b,h) x pair p (128-row tiles 15-p, p) x kv-parity part(4).
// 4 waves x 32 q-rows (strips A,B of 16): every K/V LDS fragment feeds TWO
// MFMA -> LDS reads/work 1.8x lower than 16-row waves. V frags preloaded to
// regs so P-B overlays the consumed V buffer (P-A overlays K). m init -1e20
// vs mask -1e30 so fully-masked tiles give exp2(-1e30+1e20)=0, never exp2(0).
__global__ __launch_bounds__(256, 3)
void attn_k(const u16* __restrict__ Q, const u16* __restrict__ K,
            const u16* __restrict__ Vt, u16* __restrict__ Opart,
            float2* __restrict__ ML)
{
  __shared__ u16 Kls[2][64 * 64];  // K tile; after consumed, P-A tiles
  __shared__ u16 Vls[2][64 * 64];  // V^T tile; after consumed, P-B tiles

  const int t = threadIdx.x, w = t >> 6, l = t & 63;
  const int l4 = l >> 4, l15 = l & 15;

  int bid = blockIdx.x;
  bid = (bid & 7) * 128 + (bid >> 3); // XCD-contiguous remap (4 (b,h) per XCD)
  const int part = bid & 3, p = (bid >> 2) & 7, h = (bid >> 5) & 15, b = bid >> 9;

  const int bh = b * Hc + h;
  const u16* Qb = Q + (size_t)bh * Sc * DKc;
  const u16* Kb = K + (size_t)bh * Sc * DKc;
  const u16* Vb = Vt + (size_t)bh * DKc * Sc;
  const int swz = (l15 & 7) << 4;

  const int qt0 = 15 - p, qt1 = p; // 128-row q-tiles
  const int q00 = qt0 * 128 + w * 32, q01 = qt1 * 128 + w * 32;
  const int n0 = (2 * qt0 + 5 - part) >> 2; // count of kt===part (mod 4) in [0,2(qt0+1))
  const int n1 = (2 * qt1 + 5 - part) >> 2;
  const int ntot = n0 + n1;

  int srow[2], scol[2];
#pragma unroll
  for (int j = 0; j < 2; ++j) {
    const int e = j * 256 + t;
    srow[j] = e >> 3;
    scol[j] = (((e & 7) * 16) ^ ((srow[j] & 7) << 4)) >> 1;
  }
  auto stage = [&](int buf, int kv0) {
#pragma unroll
    for (int j = 0; j < 2; ++j) {
      const u16* gk = Kb + (size_t)(kv0 + srow[j]) * DKc + scol[j];
      __builtin_amdgcn_global_load_lds((const __attribute__((address_space(1))) void*)gk,
          (__attribute__((address_space(3))) void*)(&Kls[buf][0] + (j * 256 + w * 64) * 8), 16, 0, 0);
    }
#pragma unroll
    for (int j = 0; j < 2; ++j) {
      const u16* gv = Vb + (size_t)srow[j] * Sc + kv0 + scol[j];
      __builtin_amdgcn_global_load_lds((const __attribute__((address_space(1))) void*)gv,
          (__attribute__((address_space(3))) void*)(&Vls[buf][0] + (j * 256 + w * 64) * 8), 16, 0, 0);
    }
  };
  auto kvof = [&](int i) {
    return ((i < n0) ? (part + 4 * i) : (part + 4 * (i - n0))) * 64;
  };

  short8 qA0 = *(const short8*)(Qb + (size_t)(q00 + l15) * DKc + l4 * 8);
  short8 qA1 = *(const short8*)(Qb + (size_t)(q00 + l15) * DKc + 32 + l4 * 8);
  short8 qB0 = *(const short8*)(Qb + (size_t)(q00 + 16 + l15) * DKc + l4 * 8);
  short8 qB1 = *(const short8*)(Qb + (size_t)(q00 + 16 + l15) * DKc + 32 + l4 * 8);

  f32x4 oA[4] = {}, oB[4] = {};
  float mA = -1e20f, mB = -1e20f, lsA = 0.f, lsB = 0.f;
  int qcur = q00;

  auto epi = [&](int qbase) {
    const size_t pbase = ((size_t)part * Bc * Hc + bh) * Sc;
    if (l < 16) ML[pbase + qbase + l15] = make_float2(mA, lsA);
    else if (l < 32) ML[pbase + qbase + 16 + l15] = make_float2(mB, lsB);
#pragma unroll
    for (int dc = 0; dc < 4; ++dc)
#pragma unroll
      for (int r = 0; r < 4; ++r) {
        Opart[(pbase + qbase + l4 * 4 + r) * 64 + dc * 16 + l15] =
            (u16)cvtpk(oA[dc][r], oA[dc][r]);
        Opart[(pbase + qbase + 16 + l4 * 4 + r) * 64 + dc * 16 + l15] =
            (u16)cvtpk(oB[dc][r], oB[dc][r]);
      }
  };

  stage(0, kvof(0)); // prologue
  for (int i = 0; i < ntot; ++i) {
    const int buf = i & 1;
    const int kv0 = kvof(i);
    asm volatile("s_waitcnt vmcnt(0)" ::: "memory"); // current buf's DMA landed
    __builtin_amdgcn_s_barrier(); // + all waves done with the other buf
    if (i + 1 < ntot) stage(buf ^ 1, kvof(i + 1));

    const char* Kbuf = (const char*)&Kls[buf][0];
    const char* Vbuf = (const char*)&Vls[buf][0];
    char* PwA = (char*)&Kls[buf][0] + w * 2048;
    char* PwB = (char*)&Vls[buf][0] + w * 2048;

    // QK: each K frag feeds both q-strips
    f32x4 scA[4], scB[4];
    __builtin_amdgcn_s_setprio(1);
#pragma unroll
    for (int c = 0; c < 4; ++c) {
      const int rb = (c * 16 + l15) * 128;
      const short8 ka  = *(const short8*)(Kbuf + rb + ((l4 * 16) ^ swz));
      const short8 kb2 = *(const short8*)(Kbuf + rb + ((64 + l4 * 16) ^ swz));
      f32x4 zA = {0.f, 0.f, 0.f, 0.f}, zB = {0.f, 0.f, 0.f, 0.f};
      zA = __builtin_amdgcn_mfma_f32_16x16x32_bf16(ka, qA0, zA, 0, 0, 0);
      zA = __builtin_amdgcn_mfma_f32_16x16x32_bf16(kb2, qA1, zA, 0, 0, 0);
      zB = __builtin_amdgcn_mfma_f32_16x16x32_bf16(ka, qB0, zB, 0, 0, 0);
      zB = __builtin_amdgcn_mfma_f32_16x16x32_bf16(kb2, qB1, zB, 0, 0, 0);
      scA[c] = zA; scB[c] = zB;
    }
    __builtin_amdgcn_s_setprio(0);

    // V frags to regs (must drain before mid barrier; latency hides under softmax)
    short8 vf[2][4];
#pragma unroll
    for (int kv2 = 0; kv2 < 2; ++kv2)
#pragma unroll
      for (int dc = 0; dc < 4; ++dc)
        vf[kv2][dc] = *(const short8*)(Vbuf + (dc * 16 + l15) * 128 + ((kv2 * 64 + l4 * 16) ^ swz));

    // causal masks per strip
    if (kv0 + 63 > qcur) {
#pragma unroll
      for (int c = 0; c < 4; ++c) {
        const int kvr = kv0 + c * 16 + l4 * 4;
#pragma unroll
        for (int r = 0; r < 4; ++r)
          if (kvr + r > qcur + l15) scA[c][r] = -1e30f;
      }
    }
    if (kv0 + 63 > qcur + 16) {
#pragma unroll
      for (int c = 0; c < 4; ++c) {
        const int kvr = kv0 + c * 16 + l4 * 4;
#pragma unroll
        for (int r = 0; r < 4; ++r)
          if (kvr + r > qcur + 16 + l15) scB[c][r] = -1e30f;
      }
    }

    // online softmax, exp2 domain, defer-max (THR=8), two strips
    float pmA = -1e30f, pmB = -1e30f;
#pragma unroll
    for (int c = 0; c < 4; ++c) {
      pmA = fmaxf(pmA, fmaxf(fmaxf(scA[c][0], scA[c][1]), fmaxf(scA[c][2], scA[c][3])));
      pmB = fmaxf(pmB, fmaxf(fmaxf(scB[c][0], scB[c][1]), fmaxf(scB[c][2], scB[c][3])));
    }
    pmA = fmaxf(pmA, __shfl_xor(pmA, 16)); pmA = fmaxf(pmA, __shfl_xor(pmA, 32));
    pmB = fmaxf(pmB, __shfl_xor(pmB, 16)); pmB = fmaxf(pmB, __shfl_xor(pmB, 32));
    if (!__all(fmaxf(pmA - mA, pmB - mB) <= 8.0f)) {
      const float mnA = fmaxf(mA, pmA), mnB = fmaxf(mB, pmB);
      const float fA = EXP2F(mA - mnA), fB = EXP2F(mB - mnB);
      float f4A[4], f4B[4];
#pragma unroll
      for (int r = 0; r < 4; ++r) {
        f4A[r] = __shfl(fA, l4 * 4 + r);
        f4B[r] = __shfl(fB, l4 * 4 + r);
      }
#pragma unroll
      for (int dc = 0; dc < 4; ++dc)
#pragma unroll
        for (int r = 0; r < 4; ++r) { oA[dc][r] *= f4A[r]; oB[dc][r] *= f4B[r]; }
      lsA *= fA; lsB *= fB; mA = mnA; mB = mnB;
    }
    float rsA = 0.f, rsB = 0.f;
    u32 pkA[4][2], pkB[4][2];
#pragma unroll
    for (int c = 0; c < 4; ++c) {
      const float a0 = EXP2F(scA[c][0] - mA), a1 = EXP2F(scA[c][1] - mA);
      const float a2 = EXP2F(scA[c][2] - mA), a3 = EXP2F(scA[c][3] - mA);
      rsA += (a0 + a1) + (a2 + a3);
      pkA[c][0] = cvtpk(a0, a1); pkA[c][1] = cvtpk(a2, a3);
      const float b0 = EXP2F(scB[c][0] - mB), b1 = EXP2F(scB[c][1] - mB);
      const float b2 = EXP2F(scB[c][2] - mB), b3 = EXP2F(scB[c][3] - mB);
      rsB += (b0 + b1) + (b2 + b3);
      pkB[c][0] = cvtpk(b0, b1); pkB[c][1] = cvtpk(b2, b3);
    }
    rsA += __shfl_xor(rsA, 16); rsA += __shfl_xor(rsA, 32);
    rsB += __shfl_xor(rsB, 16); rsB += __shfl_xor(rsB, 32);
    lsA += rsA; lsB += rsB;

    asm volatile("s_waitcnt lgkmcnt(0)" ::: "memory");
    __builtin_amdgcn_s_barrier(); // all waves' K and V reads done -> P may overlay

#pragma unroll
    for (int c = 0; c < 4; ++c) {
      uint2 uA; uA.x = pkA[c][0]; uA.y = pkA[c][1];
      *(uint2*)(PwA + ((l15 * 128 + c * 32 + l4 * 8) ^ swz)) = uA;
      uint2 uB; uB.x = pkB[c][0]; uB.y = pkB[c][1];
      *(uint2*)(PwB + ((l15 * 128 + c * 32 + l4 * 8) ^ swz)) = uB;
    }
    __builtin_amdgcn_s_setprio(1);
#pragma unroll
    for (int kv2 = 0; kv2 < 2; ++kv2) {
      const short8 paA = *(const short8*)(PwA + ((l15 * 128 + kv2 * 64 + l4 * 16) ^ swz));
      const short8 paB = *(const short8*)(PwB + ((l15 * 128 + kv2 * 64 + l4 * 16) ^ swz));
#pragma unroll
      for (int dc = 0; dc < 4; ++dc) {
        oA[dc] = __builtin_amdgcn_mfma_f32_16x16x32_bf16(paA, vf[kv2][dc], oA[dc], 0, 0, 0);
        oB[dc] = __builtin_amdgcn_mfma_f32_16x16x32_bf16(paB, vf[kv2][dc], oB[dc], 0, 0, 0);
      }
    }
    __builtin_amdgcn_s_setprio(0);
    // no tail barrier: next head barrier covers read-before-overwrite (in-wave
    // LDS FIFO ordering + MFMA operand deps drain all DS ops pre-barrier).

    if (i == n0 - 1) { // segment boundary: flush seg0, reset, load seg1 Q frags
      epi(q00);
#pragma unroll
      for (int dc = 0; dc < 4; ++dc) {
        oA[dc] = f32x4{0.f, 0.f, 0.f, 0.f};
        oB[dc] = f32x4{0.f, 0.f, 0.f, 0.f};
      }
      mA = mB = -1e20f; lsA = lsB = 0.f;
      qcur = q01;
      qA0 = *(const short8*)(Qb + (size_t)(q01 + l15) * DKc + l4 * 8);
      qA1 = *(const short8*)(Qb + (size_t)(q01 + l15) * DKc + 32 + l4 * 8);
      qB0 = *(const short8*)(Qb + (size_t)(q01 + 16 + l15) * DKc + l4 * 8);
      qB1 = *(const short8*)(Qb + (size_t)(q01 + 16 + l15) * DKc + 32 + l4 * 8);
    }
  }
  epi(q01);
}

// ---------------- split-KV combine (exp2 domain, 4 bf16 partials) -------------
__global__ __launch_bounds__(256)
void combine_k(const u16* __restrict__ Opart, const float2* __restrict__ ML,
               u16* __restrict__ Oa)
{
  const int idx = blockIdx.x * 256 + threadIdx.x; // BHS*16
  const int row = idx >> 4, c4 = idx & 15;
  float2 ml[4];
#pragma unroll
  for (int q = 0; q < 4; ++q) ml[q] = ML[(size_t)q * BHSc + row];
  const float m = fmaxf(fmaxf(ml[0].x, ml[1].x), fmaxf(ml[2].x, ml[3].x));
  float wgt[4];
  float den = 0.f;
#pragma unroll
  for (int q = 0; q < 4; ++q) { wgt[q] = EXP2F(ml[q].x - m); den += wgt[q] * ml[q].y; }
  const float inv = 1.0f / den;
  float r0 = 0.f, r1 = 0.f, r2 = 0.f, r3 = 0.f;
#pragma unroll
  for (int q = 0; q < 4; ++q) {
    const uint2 u = *(const uint2*)(Opart + ((size_t)q * BHSc + row) * 64 + c4 * 4);
    r0 += wgt[q] * b2f((u16)u.x);
    r1 += wgt[q] * b2f((u16)(u.x >> 16));
    r2 += wgt[q] * b2f((u16)u.y);
    r3 += wgt[q] * b2f((u16)(u.y >> 16));
  }
  const int s = row & (Sc - 1), bh = row >> 11, b = bh >> 4, h = bh & 15;
  uint2 pk;
  pk.x = cvtpk(r0 * inv, r1 * inv);
  pk.y = cvtpk(r2 * inv, r3 * inv);
  *(uint2*)(Oa + ((size_t)(b * Sc + s) * DMc + h * DKc + c4 * 4)) = pk;
}

// ---------------- launch ------------------------------------------------------
extern "C" void kernel_launch(void* const* d_in, const int* in_sizes, int n_in,
                              void* d_out, int out_size, void* d_ws, size_t ws_size,
                              hipStream_t stream)
{
  const float* x      = (const float*)d_in[0];
  const int*   tokpos = (const int*)d_in[1];
  const float* qkv_w  = (const float*)d_in[2];
  const float* out_w  = (const float*)d_in[3];
  float* out = (float*)d_out;

  char* ws = (char*)d_ws;
  // Overlay region: {qkv, xb, qwb} (dead after rope_reshape / QKV GEMM)
  // reused for {Opart (33.55 MB), ML (2.1 MB)} written by attn_k.
  size_t off = 0;
  u16*   qkv   = (u16*)(ws + off);                       // 25.2 MB
  u16*   xb    = (u16*)(ws + off + 25165824);            //  8.4 MB
  u16*   qwb   = (u16*)(ws + off + 33554432);            //  6.3 MB
  u16*   Opart = (u16*)(ws + off);                       // 33.55 MB (overlay)
  float2* ML   = (float2*)(ws + off + 33554432);         //  2.1 MB (overlay)
  off += 39845888;
  u16* owb = (u16*)(ws + off); off += (size_t)DMc * DMc * 2;
  u16* Qr  = (u16*)(ws + off); off += (size_t)BHSc * DKc * 2;
  u16* Kr  = (u16*)(ws + off); off += (size_t)BHSc * DKc * 2;
  u16* Vt  = (u16*)(ws + off); off += (size_t)BHSc * DKc * 2;
  u16* Oa  = (u16*)(ws + off); off += (size_t)Mc * DMc * 2;
  float2* tab = (float2*)(ws + off); off += (size_t)Sc * 32 * sizeof(float2);

  cvt3_k<<<4096, 256, 0, stream>>>(x, qkv_w, out_w, xb, qwb, owb);
  rope_table_k<<<(Sc * 32) / 256, 256, 0, stream>>>(tab);
  gemm_bt128<u16><<<dim3(Mc / 128, 3 * DMc / 128), 256, 0, stream>>>(xb, qwb, qkv, Mc, 3 * DMc, DMc);
  rope_reshape_k<<<dim3(Sc / 64, Hc, Bc), 256, 0, stream>>>(qkv, tokpos, tab, Qr, Kr, Vt);
  attn_k<<<1024, 256, 0, stream>>>(Qr, Kr, Vt, Opart, ML);
  combine_k<<<BHSc * 16 / 256, 256, 0, stream>>>(Opart, ML, Oa);
  gemm_bt128<float><<<dim3(Mc / 128, DMc / 128), 256, 0, stream>>>(Oa, owb, out, Mc, DMc, DMc);
}

// Round 13
// 121.336 us; speedup vs baseline: 1.2649x; 1.2649x over previous
//
#include <hip/hip_runtime.h>
#include <cstdint>

typedef unsigned short u16;
typedef unsigned int u32;
typedef __attribute__((ext_vector_type(8))) short short8;
typedef __attribute__((ext_vector_type(4))) float f32x4;

static constexpr int Bc = 2, Sc = 2048, DMc = 1024, Hc = 16, DKc = 64;
static constexpr int Mc = Bc * Sc; // 4096
static constexpr int BHSc = Bc * Hc * Sc; // 65536 q-rows

#if __has_builtin(__builtin_amdgcn_exp2f)
#define EXP2F(x) __builtin_amdgcn_exp2f(x)
#else
#define EXP2F(x) exp2f(x)
#endif

__device__ __forceinline__ float b2f(u16 u) { return __uint_as_float((u32)u << 16); }
__device__ __forceinline__ u16 f2b(float f) {
  u32 x = __float_as_uint(f);
  return (u16)((x + 0x7fffu + ((x >> 16) & 1u)) >> 16);
}
// single-instruction packed f32x2 -> bf16x2 (RTNE)
__device__ __forceinline__ u32 cvtpk(float lo, float hi) {
  u32 r;
  asm("v_cvt_pk_bf16_f32 %0, %1, %2" : "=v"(r) : "v"(lo), "v"(hi));
  return r;
}

// ------- f32 -> bf16 conversion (3 inputs) + RoPE table, one launch ----------
// blocks [0,4096): convert x/qkv_w/out_w (8 f32 -> 8 bf16 per thread).
// blocks [4096,4128): fill tab[S][32] cos/sin (exp2-domain scale applied later).
__global__ __launch_bounds__(256)
void cvt3_k(const float* __restrict__ x, const float* __restrict__ qw,
            const float* __restrict__ ow,
            u16* __restrict__ xb, u16* __restrict__ qwb, u16* __restrict__ owb,
            float2* __restrict__ tab)
{
  if (blockIdx.x >= 4096) {
    const int idx = (blockIdx.x - 4096) * 256 + threadIdx.x; // S*32 total
    const int p = idx >> 5, i = idx & 31;
    const float invf = powf(10000.0f, -(float)(2 * i) / 64.0f);
    const float ang = (float)p * invf;
    tab[idx] = make_float2(cosf(ang), sinf(ang));
    return;
  }
  const int i = blockIdx.x * 256 + threadIdx.x; // 1048576 total, 8 elems each
  const float* src; u16* dst; int j;
  if (i < 524288)      { src = x;  dst = xb;  j = i; }
  else if (i < 917504) { src = qw; dst = qwb; j = i - 524288; }
  else                 { src = ow; dst = owb; j = i - 917504; }
  const float4 a = *(const float4*)(src + (size_t)j * 8);
  const float4 b = *(const float4*)(src + (size_t)j * 8 + 4);
  uint4 o;
  o.x = cvtpk(a.x, a.y);
  o.y = cvtpk(a.z, a.w);
  o.z = cvtpk(b.x, b.y);
  o.w = cvtpk(b.z, b.w);
  *(uint4*)(dst + (size_t)j * 8) = o;
}

// ---------------- GEMM: C[M][N] = A[M][K] * W[N][K]^T, bf16 in, f32 acc -------
template <typename OutT>
__global__ __launch_bounds__(256, 2)
void gemm_bt128(const u16* __restrict__ A, const u16* __restrict__ W,
                OutT* __restrict__ C, int M, int N, int K)
{
  __shared__ u16 As[128 * 32];
  __shared__ u16 Bs[128 * 32];
  const int t = threadIdx.x;
  const int w = t >> 6, l = t & 63;
  const int wr = w >> 1, wc = w & 1;
  const int l4 = l >> 4, l15 = l & 15;
  const int bm = blockIdx.x, bn = blockIdx.y;

  f32x4 acc[4][4] = {};

  const int rowA = bm * 128, rowB = bn * 128;
  const int sr = l >> 2, sk = (l & 3) * 8;

  for (int k0 = 0; k0 < K; k0 += 32) {
    __syncthreads();
#pragma unroll
    for (int i = 0; i < 2; ++i) {
      const int chunk = i * 4 + w;
      const u16* ga = A + (size_t)(rowA + chunk * 16 + sr) * K + k0 + sk;
      const u16* gb = W + (size_t)(rowB + chunk * 16 + sr) * K + k0 + sk;
      __builtin_amdgcn_global_load_lds((const __attribute__((address_space(1))) void*)ga,
                                       (__attribute__((address_space(3))) void*)(As + chunk * 512), 16, 0, 0);
      __builtin_amdgcn_global_load_lds((const __attribute__((address_space(1))) void*)gb,
                                       (__attribute__((address_space(3))) void*)(Bs + chunk * 512), 16, 0, 0);
    }
    __syncthreads();
    short8 af[4], bf[4];
#pragma unroll
    for (int m = 0; m < 4; ++m)
      af[m] = *(const short8*)(As + (wr * 64 + m * 16 + l15) * 32 + l4 * 8);
#pragma unroll
    for (int n = 0; n < 4; ++n)
      bf[n] = *(const short8*)(Bs + (wc * 64 + n * 16 + l15) * 32 + l4 * 8);
#pragma unroll
    for (int m = 0; m < 4; ++m)
#pragma unroll
      for (int n = 0; n < 4; ++n)
        acc[m][n] = __builtin_amdgcn_mfma_f32_16x16x32_bf16(af[m], bf[n], acc[m][n], 0, 0, 0);
  }

#pragma unroll
  for (int m = 0; m < 4; ++m) {
    const int r0 = rowA + wr * 64 + m * 16 + l4 * 4;
#pragma unroll
    for (int n = 0; n < 4; ++n) {
      const int c0 = rowB + wc * 64 + n * 16 + l15;
#pragma unroll
      for (int r = 0; r < 4; ++r) {
        const float v = acc[m][n][r];
        if constexpr (sizeof(OutT) == 2)
          C[(size_t)(r0 + r) * N + c0] = (OutT)f2b(v);
        else
          C[(size_t)(r0 + r) * N + c0] = (OutT)v;
      }
    }
  }
}

// ---------------- RoPE apply + relayout ---------------------------------------
// Q is scaled by 0.125*log2(e) so attention scores are in the exp2 domain.
__global__ __launch_bounds__(256)
void rope_reshape_k(const u16* __restrict__ qkv, const int* __restrict__ tokpos,
                    const float2* __restrict__ tab,
                    u16* __restrict__ Q, u16* __restrict__ K, u16* __restrict__ Vt)
{
  __shared__ u16 Vs[64][72];
  const int t = threadIdx.x;
  const int st = blockIdx.x, h = blockIdx.y, b = blockIdx.z;

  {
    const int sl = t >> 2, iq = t & 3;
    const int s = st * 64 + sl;
    const int p = tokpos[b * Sc + s];
    const size_t row = (size_t)(b * Sc + s) * 3 * DMc + h * DKc + iq * 16;
    const size_t orow = ((size_t)(b * Hc + h) * Sc + s) * DKc + iq * 16;
#pragma unroll
    for (int which = 0; which < 2; ++which) {
      const u16* g = qkv + row + which * DMc;
      uint4 va = *(const uint4*)g;
      uint4 vb = *(const uint4*)(g + 8);
      u32 in[8] = {va.x, va.y, va.z, va.w, vb.x, vb.y, vb.z, vb.w};
      const float scale = (which == 0) ? 0.18033688011112f : 1.0f; // 0.125*log2e
      u32 ow[8];
#pragma unroll
      for (int j = 0; j < 8; ++j) {
        const float2 cs = tab[p * 32 + iq * 8 + j];
        const float t1 = b2f((u16)(in[j] & 0xffffu));
        const float t2 = b2f((u16)(in[j] >> 16));
        ow[j] = cvtpk((t1 * cs.x - t2 * cs.y) * scale, (t1 * cs.y + t2 * cs.x) * scale);
      }
      u16* dst = (which == 0 ? Q : K) + orow;
      *(uint4*)dst = make_uint4(ow[0], ow[1], ow[2], ow[3]);
      *(uint4*)(dst + 8) = make_uint4(ow[4], ow[5], ow[6], ow[7]);
    }
  }
#pragma unroll
  for (int it = 0; it < 2; ++it) {
    const int sv = it * 32 + (t >> 3);
    const int d0 = (t & 7) * 8;
    const u16* g = qkv + (size_t)(b * Sc + st * 64 + sv) * 3 * DMc + 2 * DMc + h * DKc + d0;
    *(uint4*)&Vs[sv][d0] = *(const uint4*)g;
  }
  __syncthreads();
  {
    const int d = t >> 2, s0 = (t & 3) * 16;
    u16 tmp[16];
#pragma unroll
    for (int j = 0; j < 16; ++j) tmp[j] = Vs[s0 + j][d];
    u16* dst = Vt + ((size_t)(b * Hc + h) * DKc + d) * Sc + st * 64 + s0;
    *(uint4*)dst = *(const uint4*)tmp;
    *(uint4*)(dst + 8) = *(const uint4*)(tmp + 8);
  }
}

// ---------------- causal flash attention, split-KV partials -------------------
// Round-11 structure (verified 43 us): split-KV 2-way, 1024 uniform blocks,
// 4 waves x 16 q-rows, P overlays consumed K LDS, exp2 softmax, defer-max,
// cvt_pk, setprio, 2 barriers/iter, bf16 partials.
__global__ __launch_bounds__(256, 4)
void attn_k(const u16* __restrict__ Q, const u16* __restrict__ K,
            const u16* __restrict__ Vt, u16* __restrict__ Opart,
            float2* __restrict__ ML)
{
  __shared__ u16 Kls[2][64 * 64];  // K tile; after K consumed, also P tiles
  __shared__ u16 Vls[2][64 * 64];  // V^T tile

  const int t = threadIdx.x, w = t >> 6, l = t & 63;
  const int l4 = l >> 4, l15 = l & 15;

  int bid = blockIdx.x;
  bid = (bid & 7) * 128 + (bid >> 3); // XCD-contiguous remap (4 (b,h) per XCD)
  const int p = bid & 15, part = (bid >> 4) & 1, h = (bid >> 5) & 15, b = bid >> 9;

  const int bh = b * Hc + h;
  const u16* Qb = Q + (size_t)bh * Sc * DKc;
  const u16* Kb = K + (size_t)bh * Sc * DKc;
  const u16* Vb = Vt + (size_t)bh * DKc * Sc;
  const int swz = (l15 & 7) << 4;

  const int qt0 = 31 - p, qt1 = p;
  const int q00 = qt0 * 64 + w * 16, q01 = qt1 * 64 + w * 16;
  const int n0 = (qt0 + 2 - part) >> 1, n1 = (qt1 + 2 - part) >> 1;
  const int ntot = n0 + n1;

  const short8 qf0a = *(const short8*)(Qb + (size_t)(q00 + l15) * DKc + l4 * 8);
  const short8 qf0b = *(const short8*)(Qb + (size_t)(q00 + l15) * DKc + 32 + l4 * 8);
  const short8 qf1a = *(const short8*)(Qb + (size_t)(q01 + l15) * DKc + l4 * 8);
  const short8 qf1b = *(const short8*)(Qb + (size_t)(q01 + l15) * DKc + 32 + l4 * 8);

  int srow[2], scol[2];
#pragma unroll
  for (int j = 0; j < 2; ++j) {
    const int e = j * 256 + t;
    srow[j] = e >> 3;
    scol[j] = (((e & 7) * 16) ^ ((srow[j] & 7) << 4)) >> 1;
  }
  auto stage = [&](int buf, int kv0) {
#pragma unroll
    for (int j = 0; j < 2; ++j) {
      const u16* gk = Kb + (size_t)(kv0 + srow[j]) * DKc + scol[j];
      __builtin_amdgcn_global_load_lds((const __attribute__((address_space(1))) void*)gk,
          (__attribute__((address_space(3))) void*)(&Kls[buf][0] + (j * 256 + w * 64) * 8), 16, 0, 0);
    }
#pragma unroll
    for (int j = 0; j < 2; ++j) {
      const u16* gv = Vb + (size_t)srow[j] * Sc + kv0 + scol[j];
      __builtin_amdgcn_global_load_lds((const __attribute__((address_space(1))) void*)gv,
          (__attribute__((address_space(3))) void*)(&Vls[buf][0] + (j * 256 + w * 64) * 8), 16, 0, 0);
    }
  };
  auto kvof = [&](int i) {
    return ((i < n0) ? (part + 2 * i) : (part + 2 * (i - n0))) * 64;
  };

  f32x4 o[4] = {};
  float m = -1e30f, lsum = 0.f;
  int qcur = q00;
  short8 qfA = qf0a, qfB = qf0b;

  auto epi = [&](int qbase) {
    const size_t pbase = ((size_t)part * Bc * Hc + bh) * Sc;
    if (l < 16) ML[pbase + qbase + l15] = make_float2(m, lsum);
#pragma unroll
    for (int dc = 0; dc < 4; ++dc)
#pragma unroll
      for (int r = 0; r < 4; ++r)
        Opart[(pbase + qbase + l4 * 4 + r) * 64 + dc * 16 + l15] =
            (u16)cvtpk(o[dc][r], o[dc][r]);
  };

  stage(0, kvof(0)); // prologue
  for (int i = 0; i < ntot; ++i) {
    const int buf = i & 1;
    const int kv0 = kvof(i);
    asm volatile("s_waitcnt vmcnt(0)" ::: "memory"); // current buf's DMA landed
    __builtin_amdgcn_s_barrier(); // + all waves done reading the other buf
    if (i + 1 < ntot) stage(buf ^ 1, kvof(i + 1)); // overwrite is now safe

    const char* Kbuf = (const char*)&Kls[buf][0];
    const char* Vbuf = (const char*)&Vls[buf][0];
    char* Pw = (char*)&Kls[buf][0] + w * 2048; // P overlays consumed K

    f32x4 sc[4];
    __builtin_amdgcn_s_setprio(1);
#pragma unroll
    for (int c = 0; c < 4; ++c) {
      const int rb = (c * 16 + l15) * 128;
      const short8 ka  = *(const short8*)(Kbuf + rb + ((l4 * 16) ^ swz));
      const short8 kb2 = *(const short8*)(Kbuf + rb + ((64 + l4 * 16) ^ swz));
      f32x4 z = {0.f, 0.f, 0.f, 0.f};
      z = __builtin_amdgcn_mfma_f32_16x16x32_bf16(ka, qfA, z, 0, 0, 0);
      z = __builtin_amdgcn_mfma_f32_16x16x32_bf16(kb2, qfB, z, 0, 0, 0);
      sc[c] = z;
    }
    __builtin_amdgcn_s_setprio(0);
    if (kv0 + 63 > qcur) { // diagonal tile only
#pragma unroll
      for (int c = 0; c < 4; ++c) {
        const int kvr = kv0 + c * 16 + l4 * 4;
#pragma unroll
        for (int r = 0; r < 4; ++r)
          if (kvr + r > qcur + l15) sc[c][r] = -1e30f;
      }
    }
    // online softmax, exp2 domain, defer-max (THR=8)
    float pmax = -1e30f;
#pragma unroll
    for (int c = 0; c < 4; ++c)
      pmax = fmaxf(pmax, fmaxf(fmaxf(sc[c][0], sc[c][1]), fmaxf(sc[c][2], sc[c][3])));
    pmax = fmaxf(pmax, __shfl_xor(pmax, 16));
    pmax = fmaxf(pmax, __shfl_xor(pmax, 32));
    if (!__all(pmax - m <= 8.0f)) { // rare: rescale needed
      const float mnew = fmaxf(m, pmax);
      const float fac = EXP2F(m - mnew);
      float f4[4];
#pragma unroll
      for (int r = 0; r < 4; ++r) f4[r] = __shfl(fac, l4 * 4 + r);
#pragma unroll
      for (int dc = 0; dc < 4; ++dc) {
        o[dc][0] *= f4[0]; o[dc][1] *= f4[1];
        o[dc][2] *= f4[2]; o[dc][3] *= f4[3];
      }
      lsum *= fac;
      m = mnew;
    }
    float rs = 0.f;
    u32 pk[4][2];
#pragma unroll
    for (int c = 0; c < 4; ++c) {
      const float p0 = EXP2F(sc[c][0] - m);
      const float p1 = EXP2F(sc[c][1] - m);
      const float p2 = EXP2F(sc[c][2] - m);
      const float p3 = EXP2F(sc[c][3] - m);
      rs += (p0 + p1) + (p2 + p3);
      pk[c][0] = cvtpk(p0, p1);
      pk[c][1] = cvtpk(p2, p3);
    }
    rs += __shfl_xor(rs, 16);
    rs += __shfl_xor(rs, 32);
    lsum += rs;

    asm volatile("s_waitcnt lgkmcnt(0)" ::: "memory");
    __builtin_amdgcn_s_barrier(); // ALL waves finished K reads -> safe to write P

#pragma unroll
    for (int c = 0; c < 4; ++c) {
      uint2 u; u.x = pk[c][0]; u.y = pk[c][1];
      *(uint2*)(Pw + ((l15 * 128 + c * 32 + l4 * 8) ^ swz)) = u;
    }
    __builtin_amdgcn_s_setprio(1);
#pragma unroll
    for (int kv2 = 0; kv2 < 2; ++kv2) {
      const short8 pa = *(const short8*)(Pw + ((l15 * 128 + kv2 * 64 + l4 * 16) ^ swz));
#pragma unroll
      for (int dc = 0; dc < 4; ++dc) {
        const short8 vf = *(const short8*)(Vbuf + (dc * 16 + l15) * 128 + ((kv2 * 64 + l4 * 16) ^ swz));
        o[dc] = __builtin_amdgcn_mfma_f32_16x16x32_bf16(pa, vf, o[dc], 0, 0, 0);
      }
    }
    __builtin_amdgcn_s_setprio(0);
    // no tail barrier: next iteration's head barrier covers the read-before-
    // overwrite hazard (each wave's ds_reads drained by MFMA operand deps).

    if (i == n0 - 1) { // segment boundary: flush seg0, reset state
      epi(q00);
#pragma unroll
      for (int dc = 0; dc < 4; ++dc) o[dc] = f32x4{0.f, 0.f, 0.f, 0.f};
      m = -1e30f; lsum = 0.f;
      qcur = q01; qfA = qf1a; qfB = qf1b;
    }
  }
  epi(q01);
}

// ---------------- split-KV combine (exp2 domain, bf16 partials) ---------------
__global__ __launch_bounds__(256)
void combine_k(const u16* __restrict__ Opart, const float2* __restrict__ ML,
               u16* __restrict__ Oa)
{
  const int idx = blockIdx.x * 256 + threadIdx.x; // BHS*16
  const int row = idx >> 4, c4 = idx & 15;
  const float2 a = ML[row], bm2 = ML[BHSc + row];
  const float m = fmaxf(a.x, bm2.x);
  const float w0 = EXP2F(a.x - m), w1 = EXP2F(bm2.x - m);
  const float inv = 1.0f / (w0 * a.y + w1 * bm2.y);
  const uint2 u0 = *(const uint2*)(Opart + (size_t)row * 64 + c4 * 4);
  const uint2 u1 = *(const uint2*)(Opart + ((size_t)BHSc + row) * 64 + c4 * 4);
  const float r0 = (w0 * b2f((u16)u0.x) + w1 * b2f((u16)u1.x)) * inv;
  const float r1 = (w0 * b2f((u16)(u0.x >> 16)) + w1 * b2f((u16)(u1.x >> 16))) * inv;
  const float r2 = (w0 * b2f((u16)u0.y) + w1 * b2f((u16)u1.y)) * inv;
  const float r3 = (w0 * b2f((u16)(u0.y >> 16)) + w1 * b2f((u16)(u1.y >> 16))) * inv;
  const int s = row & (Sc - 1), bh = row >> 11, b = bh >> 4, h = bh & 15;
  uint2 pk;
  pk.x = cvtpk(r0, r1);
  pk.y = cvtpk(r2, r3);
  *(uint2*)(Oa + ((size_t)(b * Sc + s) * DMc + h * DKc + c4 * 4)) = pk;
}

// ---------------- launch ------------------------------------------------------
extern "C" void kernel_launch(void* const* d_in, const int* in_sizes, int n_in,
                              void* d_out, int out_size, void* d_ws, size_t ws_size,
                              hipStream_t stream)
{
  const float* x      = (const float*)d_in[0];
  const int*   tokpos = (const int*)d_in[1];
  const float* qkv_w  = (const float*)d_in[2];
  const float* out_w  = (const float*)d_in[3];
  float* out = (float*)d_out;

  char* ws = (char*)d_ws;
  // Overlay region: {qkv, xb, qwb} (dead after rope_reshape / QKV GEMM)
  // reused for {Opart, ML} (written by attn_k).
  size_t off = 0;
  u16*   qkv   = (u16*)(ws + off);                       // 25.2 MB
  u16*   xb    = (u16*)(ws + off + 25165824);            //  8.4 MB
  u16*   qwb   = (u16*)(ws + off + 33554432);            //  6.3 MB
  u16*   Opart = (u16*)(ws + off);                       // 16.8 MB (overlay)
  float2* ML   = (float2*)(ws + off + 33554432);         //  1.0 MB (overlay)
  off += 39845888;
  u16* owb = (u16*)(ws + off); off += (size_t)DMc * DMc * 2;
  u16* Qr  = (u16*)(ws + off); off += (size_t)BHSc * DKc * 2;
  u16* Kr  = (u16*)(ws + off); off += (size_t)BHSc * DKc * 2;
  u16* Vt  = (u16*)(ws + off); off += (size_t)BHSc * DKc * 2;
  u16* Oa  = (u16*)(ws + off); off += (size_t)Mc * DMc * 2;
  float2* tab = (float2*)(ws + off); off += (size_t)Sc * 32 * sizeof(float2);

  cvt3_k<<<4096 + (Sc * 32) / 256, 256, 0, stream>>>(x, qkv_w, out_w, xb, qwb, owb, tab);
  gemm_bt128<u16><<<dim3(Mc / 128, 3 * DMc / 128), 256, 0, stream>>>(xb, qwb, qkv, Mc, 3 * DMc, DMc);
  rope_reshape_k<<<dim3(Sc / 64, Hc, Bc), 256, 0, stream>>>(qkv, tokpos, tab, Qr, Kr, Vt);
  attn_k<<<1024, 256, 0, stream>>>(Qr, Kr, Vt, Opart, ML);
  combine_k<<<BHSc * 16 / 256, 256, 0, stream>>>(Opart, ML, Oa);
  gemm_bt128<float><<<dim3(Mc / 128, DMc / 128), 256, 0, stream>>>(Oa, owb, out, Mc, DMc, DMc);
}